// Round 20
// baseline (314.398 us; speedup 1.0000x reference)
//
#include <hip/hip_runtime.h>
#include <math.h>

#define BSZ 32
#define CH  256

typedef short  bf16x8 __attribute__((ext_vector_type(8)));
typedef float  f32x4  __attribute__((ext_vector_type(4)));
typedef unsigned short ushort_t;
typedef unsigned int   uint_t;

#define MFMA(a, b, c) __builtin_amdgcn_mfma_f32_16x16x32_bf16((a), (b), (c), 0, 0, 0)

__device__ __forceinline__ ushort_t f2b(float f) {
    uint_t u = __builtin_bit_cast(uint_t, f);
    uint_t r = (u + 0x7FFFu + ((u >> 16) & 1u)) >> 16;   // RTNE
    return (ushort_t)r;
}
__device__ __forceinline__ float b2f(ushort_t u) {
    uint_t v = ((uint_t)u) << 16;
    return __builtin_bit_cast(float, v);
}
__device__ __forceinline__ uint_t pk2(float a, float b) {
    return (uint_t)f2b(a) | ((uint_t)f2b(b) << 16);
}

// ---------------- kernel 1: per-cell winning edge (last write wins) -------
__global__ void edge_win_kernel(const int* __restrict__ ei, int E, int nb,
                                int* __restrict__ win) {
    int e = blockIdx.x * blockDim.x + threadIdx.x;
    if (e >= E) return;
    int r = ei[e];
    int c = ei[E + e];
    int br = r >> 5, bc = c >> 5;
    if (br == bc && br < nb) {
        atomicMax(&win[br * (BSZ * BSZ) + (r & 31) * BSZ + (c & 31)], e);
    }
}

// ---------------- kernel 2: weights->frag layout + per-node gate proj -----
// blocks [0,96): wconv (qkv 48 tiles + proj 16 tiles, fragment layout)
// blocks [96,..): pg[h*N+n] = dot(pos[n], gate_w[h][0:3])
__global__ void prep_kernel(const float* __restrict__ qkv_w,
                            const float* __restrict__ proj_w,
                            ushort_t* __restrict__ qkv_wf,
                            ushort_t* __restrict__ proj_wf,
                            const float* __restrict__ pos,
                            const float* __restrict__ gate_w,
                            float* __restrict__ pg, int N) {
    int b = blockIdx.x;
    if (b < 96) {
        int i = b * 256 + threadIdx.x;   // (tile,ks,lane)
        int lane = i & 63, ks = (i >> 6) & 7, tile = i >> 9;
        int l15 = lane & 15, lg = lane >> 4;
        if (tile < 48) {
            const float* src = qkv_w + (size_t)(tile * 16 + l15) * 256 + ks * 32 + lg * 8;
            ushort_t* dst = qkv_wf + (size_t)i * 8;
            #pragma unroll
            for (int e = 0; e < 8; ++e) dst[e] = f2b(src[e]);
        }
        if (tile < 16) {
            const float* src = proj_w + (size_t)(tile * 16 + l15) * 256 + ks * 32 + lg * 8;
            ushort_t* dst = proj_wf + (size_t)i * 8;
            #pragma unroll
            for (int e = 0; e < 8; ++e) dst[e] = f2b(src[e]);
        }
    } else {
        int idx = (b - 96) * 256 + threadIdx.x;   // 0 .. 4N-1
        if (idx >= 4 * N) return;
        int h = idx / N;
        int n = idx - h * N;
        pg[(size_t)h * N + n] = pos[n * 3 + 0] * gate_w[h * 4 + 0]
                              + pos[n * 3 + 1] * gate_w[h * 4 + 1]
                              + pos[n * 3 + 2] * gate_w[h * 4 + 2];
    }
}

// ---------------- fused kernel: BM=64, wave = head, in-wave everything ----
// R17 body (measured wall-best 223.5 us), launch_bounds(256,4): target 4
// independent WGs/CU (LDS 37.9K x4 = 151.6K fits; VGPR 124 <= 128).
// Independent per-WG barriers let one WG's MFMA cover another's weight-load
// stalls (unlike R15's single-barrier-domain 1024-thread test).
// LDS: xb 32K (-> xo overlay post-B2) + scr 4x1216 = 37632 B.
#define LS_SCR 32768
#define LS_TOT 37632

__global__ __launch_bounds__(256, 4)
void fused_attn(const float* __restrict__ x,
                const ushort_t* __restrict__ qkv_wf,
                const float* __restrict__ qkv_b,
                const int* __restrict__ win,
                const float* __restrict__ ev,
                const float* __restrict__ pg,
                const ushort_t* __restrict__ proj_wf,
                const float* __restrict__ proj_b,
                const float* __restrict__ gate_w,
                const float* __restrict__ gate_b,
                float* __restrict__ out, int N)
{
    __shared__ __align__(16) char smem[LS_TOT];
    ushort_t* xb = (ushort_t*)(smem);
    ushort_t* xo = (ushort_t*)(smem);      // overlay: xb dead post-B2

    const int t = threadIdx.x;
    const int h = t >> 6, lane = t & 63, l15 = lane & 15, lg = lane >> 4;
    const int bi = blockIdx.x, mbase = bi * 64;
    ushort_t* scr = (ushort_t*)(smem + LS_SCR + h * 1216);

    // ---- P1: stage x -> bf16 LDS (swz8) ---------------------------------
    #pragma unroll
    for (int i = 0; i < 16; ++i) {
        int flat = i * 1024 + t * 4;
        int r = flat >> 8, c = flat & 255;
        float4 xv = *(const float4*)&x[(size_t)(mbase + r) * CH + c];
        uint2 wv; wv.x = pk2(xv.x, xv.y); wv.y = pk2(xv.z, xv.w);
        *(uint2*)&xb[r * 256 + (c ^ ((r & 7) << 3))] = wv;
    }
    __syncthreads();   // B1

    const int slB = (l15 & 7) << 3;
    const f32x4 zf = {0.f, 0.f, 0.f, 0.f};

    // wave-private 16x32 repack (R10-proven): D-frag pair -> A/B-frag.
    auto repack16 = [&](f32x4 a0, f32x4 a1) -> bf16x8 {
        uint2 w0, w1;
        w0.x = pk2(a0[0], a0[1]); w0.y = pk2(a0[2], a0[3]);
        w1.x = pk2(a1[0], a1[1]); w1.y = pk2(a1[2], a1[3]);
        *(uint2*)&scr[l15 * 38 + lg * 4]      = w0;
        *(uint2*)&scr[l15 * 38 + 16 + lg * 4] = w1;
        return *(const bf16x8*)&scr[l15 * 38 + lg * 8];
    };

    bf16x8 qld[2][2][2], kld[2][2][2], vf[2][4];

#define QK_SECTION(TB, DST)                                                   \
    _Pragma("unroll")                                                         \
    for (int p = 0; p < 2; ++p) {                                             \
        const int T0 = (TB) + p * 2, T1 = T0 + 1;                             \
        bf16x8 W0[8], W1[8];                                                  \
        _Pragma("unroll")                                                     \
        for (int ks = 0; ks < 8; ++ks) {                                      \
            W0[ks] = *(const bf16x8*)(qkv_wf                                  \
                        + ((size_t)(T0 * 8 + ks)) * 512 + lane * 8);          \
            W1[ks] = *(const bf16x8*)(qkv_wf                                  \
                        + ((size_t)(T1 * 8 + ks)) * 512 + lane * 8);          \
        }                                                                     \
        f32x4 a0[4], a1[4];                                                   \
        _Pragma("unroll")                                                     \
        for (int m = 0; m < 4; ++m) { a0[m] = zf; a1[m] = zf; }               \
        __builtin_amdgcn_s_setprio(1);                                        \
        _Pragma("unroll")                                                     \
        for (int ks = 0; ks < 8; ++ks) {                                      \
            int k0 = (ks * 32 + lg * 8) ^ slB;                                \
            _Pragma("unroll")                                                 \
            for (int m = 0; m < 4; ++m) {                                     \
                bf16x8 xf = *(const bf16x8*)&xb[(m * 16 + l15) * 256 + k0];   \
                a0[m] = MFMA(W0[ks], xf, a0[m]);                              \
                a1[m] = MFMA(W1[ks], xf, a1[m]);                              \
            }                                                                 \
        }                                                                     \
        __builtin_amdgcn_s_setprio(0);                                        \
        f32x4 b0v = *(const f32x4*)&qkv_b[T0 * 16 + lg * 4];                  \
        f32x4 b1v = *(const f32x4*)&qkv_b[T1 * 16 + lg * 4];                  \
        _Pragma("unroll")                                                     \
        for (int m = 0; m < 4; ++m) { a0[m] += b0v; a1[m] += b1v; }           \
        _Pragma("unroll")                                                     \
        for (int gl = 0; gl < 2; ++gl)                                        \
            _Pragma("unroll")                                                 \
            for (int rt = 0; rt < 2; ++rt)                                    \
                DST[gl][rt][p] = repack16(a0[gl * 2 + rt], a1[gl * 2 + rt]);  \
    }

    // ---- P2: q section (swapped: D[ch][row]) -> qld B-frags -------------
    QK_SECTION(h * 4, qld)
    // ---- P3: k section -> kld A-frags -----------------------------------
    QK_SECTION(16 + h * 4, kld)

    // ---- preload win / pgate, then HOISTED ev gathers -------------------
    uint4  wv4[2][2][2];
    float4 pgc[2][2];
    float  pgr[2][2];
    #pragma unroll
    for (int gl = 0; gl < 2; ++gl) {
        int cb = mbase + gl * 32;
        #pragma unroll
        for (int qt = 0; qt < 2; ++qt) {
            int qi = qt * 16 + l15;
            wv4[gl][qt][0] = *(const uint4*)&win[(size_t)(bi * 2 + gl) * 1024
                                                + qi * 32 + lg * 4];
            wv4[gl][qt][1] = *(const uint4*)&win[(size_t)(bi * 2 + gl) * 1024
                                                + qi * 32 + 16 + lg * 4];
            pgr[gl][qt] = pg[(size_t)h * N + cb + qi];
        }
        pgc[gl][0] = *(const float4*)&pg[(size_t)h * N + cb + lg * 4];
        pgc[gl][1] = *(const float4*)&pg[(size_t)h * N + cb + 16 + lg * 4];
    }
    // ev gathers issued HERE: resolve under the v-GEMM + B2 (off the
    // post-B2 softmax critical chain).
    float evv[2][2][8];
    #pragma unroll
    for (int gl = 0; gl < 2; ++gl)
        #pragma unroll
        for (int qt = 0; qt < 2; ++qt)
            #pragma unroll
            for (int kt = 0; kt < 2; ++kt) {
                const int* wp = (const int*)&wv4[gl][qt][kt];
                #pragma unroll
                for (int j = 0; j < 4; ++j) {
                    int e = wp[j];
                    evv[gl][qt][kt * 4 + j] = ev[e < 0 ? 0 : e];
                }
            }

    // ---- P4: v section (non-swapped: D[row][ch]) -> vf A-frags ----------
    #pragma unroll
    for (int ct = 0; ct < 4; ++ct) {
        int T = 32 + h * 4 + ct;
        bf16x8 W[8];
        #pragma unroll
        for (int ks = 0; ks < 8; ++ks)
            W[ks] = *(const bf16x8*)(qkv_wf + ((size_t)(T * 8 + ks)) * 512 + lane * 8);
        f32x4 a[4];
        #pragma unroll
        for (int m = 0; m < 4; ++m) a[m] = zf;
        __builtin_amdgcn_s_setprio(1);
        #pragma unroll
        for (int ks = 0; ks < 8; ++ks) {
            int k0 = (ks * 32 + lg * 8) ^ slB;
            #pragma unroll
            for (int m = 0; m < 4; ++m) {
                bf16x8 xf = *(const bf16x8*)&xb[(m * 16 + l15) * 256 + k0];
                a[m] = MFMA(xf, W[ks], a[m]);
            }
        }
        __builtin_amdgcn_s_setprio(0);
        float bvs = qkv_b[T * 16 + l15];
        f32x4 bb = {bvs, bvs, bvs, bvs};
        #pragma unroll
        for (int m = 0; m < 4; ++m) a[m] += bb;
        vf[0][ct] = repack16(a[0], a[1]);
        vf[1][ct] = repack16(a[2], a[3]);
    }
    __syncthreads();   // B2: all waves' xb reads done -> xo overlay safe

    const float gw3v = gate_w[h * 4 + 3];
    const float gbv  = gate_b[h];
    const float g3b  = gw3v + gbv;

    // ---- P5: per-leaf attention (all in-wave) ---------------------------
    #pragma unroll
    for (int gl = 0; gl < 2; ++gl) {
        // scores MFMA (A=k M=kj, B=q N=qi)
        f32x4 s[2][2];
        #pragma unroll
        for (int qt = 0; qt < 2; ++qt) { s[qt][0] = zf; s[qt][1] = zf; }
        __builtin_amdgcn_s_setprio(1);
        #pragma unroll
        for (int qt = 0; qt < 2; ++qt)
            #pragma unroll
            for (int p = 0; p < 2; ++p)
                #pragma unroll
                for (int kt = 0; kt < 2; ++kt)
                    s[qt][kt] = MFMA(kld[gl][kt][p], qld[gl][qt][p], s[qt][kt]);
        __builtin_amdgcn_s_setprio(0);

        // softmax + gate; kj=32 via mean of raw scores (linearity)
        bf16x8 cfr[2];
        #pragma unroll
        for (int qt = 0; qt < 2; ++qt) {
            int qi = qt * 16 + l15;
            float r[8], gt[8];
            float rawsum = 0.f;
            #pragma unroll
            for (int kt = 0; kt < 2; ++kt) {
                const int* wp = (const int*)&wv4[gl][qt][kt];
                #pragma unroll
                for (int j = 0; j < 4; ++j) {
                    int kj = kt * 16 + lg * 4 + j;
                    bool fixed = (kj == qi);
                    bool valid = wp[j] >= 0;
                    float e3 = evv[gl][qt][kt * 4 + j];
                    float sb = fixed ? 1.0f : (valid ? e3 : -INFINITY);
                    float pgcv = ((const float*)&pgc[gl][kt])[j];
                    float g = fixed ? g3b
                            : (valid ? (pgcv - pgr[gl][qt] + e3 * gw3v + gbv) : 0.0f);
                    float sraw = s[qt][kt][j];
                    rawsum += sraw;
                    r[kt * 4 + j]  = sraw * 0.125f + sb;
                    gt[kt * 4 + j] = g;
                }
            }
            rawsum += __shfl_xor(rawsum, 16);
            rawsum += __shfl_xor(rawsum, 32);
            float r2 = rawsum * (0.125f / 32.0f) + 1.0f;

            float m = fmaxf(fmaxf(fmaxf(r[0], r[1]), fmaxf(r[2], r[3])),
                            fmaxf(fmaxf(r[4], r[5]), fmaxf(r[6], r[7])));
            m = fmaxf(m, r2);
            m = fmaxf(m, __shfl_xor(m, 16));
            m = fmaxf(m, __shfl_xor(m, 32));
            float sum = 0.f;
            #pragma unroll
            for (int i = 0; i < 8; ++i) { r[i] = __expf(r[i] - m); sum += r[i]; }
            sum += __shfl_xor(sum, 16);
            sum += __shfl_xor(sum, 32);
            float e2 = __expf(r2 - m);
            float inv = 1.0f / (sum + e2);
            float comb32 = e2 * inv + g3b;
            float cadd = comb32 * 0.03125f;   // fold kj=32 PV into every entry
            f32x4 ra = {r[0] * inv + gt[0] + cadd, r[1] * inv + gt[1] + cadd,
                        r[2] * inv + gt[2] + cadd, r[3] * inv + gt[3] + cadd};
            f32x4 rb = {r[4] * inv + gt[4] + cadd, r[5] * inv + gt[5] + cadd,
                        r[6] * inv + gt[6] + cadd, r[7] * inv + gt[7] + cadd};
            cfr[qt] = repack16(ra, rb);       // B-frag: l15=qi, lg*8+e=kj
        }

        // PV MFMA (A=v M=ch, B=comb N=qi) -> xo (xb overlay)
        __builtin_amdgcn_s_setprio(1);
        #pragma unroll
        for (int ct = 0; ct < 4; ++ct) {
            #pragma unroll
            for (int qt = 0; qt < 2; ++qt) {
                f32x4 a2 = zf;
                a2 = MFMA(vf[gl][ct], cfr[qt], a2);
                int qi = qt * 16 + l15;
                uint2 wv;
                wv.x = pk2(a2[0], a2[1]);
                wv.y = pk2(a2[2], a2[3]);
                int c0 = h * 64 + ct * 16 + lg * 4;
                *(uint2*)&xo[gl * 8192 + qi * 256 + (c0 ^ ((l15 & 7) << 3))] = wv;
            }
        }
        __builtin_amdgcn_s_setprio(0);
    }
    __syncthreads();   // B3: xo read cross-wave by proj

    // ---- P6: proj (wave h: tiles h*4+i), 2-deep weight pipeline ---------
    {
        const int slR = (l15 & 7) << 3;
        bf16x8 pwA[4], pwB[4];
        f32x4 pacc[4][4];
        #pragma unroll
        for (int i = 0; i < 4; ++i)
            #pragma unroll
            for (int rt = 0; rt < 4; ++rt) pacc[i][rt] = zf;

#define LOADPW(dst, kss) { _Pragma("unroll")                                  \
        for (int i_ = 0; i_ < 4; ++i_)                                        \
            dst[i_] = *(const bf16x8*)(proj_wf                                \
                + ((size_t)((h * 4 + i_) * 8 + (kss))) * 512 + lane * 8); }

#define PCOMP(pw, kss) { int k0_ = (kss) * 32 + lg * 8;                       \
        _Pragma("unroll")                                                     \
        for (int rt_ = 0; rt_ < 4; ++rt_) {                                   \
            bf16x8 b_ = *(const bf16x8*)&xo[(rt_ >> 1) * 8192                 \
                         + ((rt_ & 1) * 16 + l15) * 256 + (k0_ ^ slR)];       \
            _Pragma("unroll")                                                 \
            for (int i_ = 0; i_ < 4; ++i_)                                    \
                pacc[i_][rt_] = MFMA(pw[i_], b_, pacc[i_][rt_]);              \
        } }

        LOADPW(pwA, 0); LOADPW(pwB, 1);
        __builtin_amdgcn_s_setprio(1);
        PCOMP(pwA, 0);  LOADPW(pwA, 2);
        PCOMP(pwB, 1);  LOADPW(pwB, 3);
        PCOMP(pwA, 2);  LOADPW(pwA, 4);
        PCOMP(pwB, 3);  LOADPW(pwB, 5);
        PCOMP(pwA, 4);  LOADPW(pwA, 6);
        PCOMP(pwB, 5);  LOADPW(pwB, 7);
        PCOMP(pwA, 6);
        PCOMP(pwB, 7);
        __builtin_amdgcn_s_setprio(0);

        #pragma unroll
        for (int i = 0; i < 4; ++i) {
            int n0 = (h * 4 + i) * 16;
            f32x4 bv = *(const f32x4*)&proj_b[n0 + lg * 4];
            #pragma unroll
            for (int rt = 0; rt < 4; ++rt) {
                f32x4 o = pacc[i][rt] + bv;
                int row = mbase + (rt >> 1) * 32 + (rt & 1) * 16 + l15;
                *(f32x4*)&out[(size_t)row * 256 + n0 + lg * 4] = o;
            }
        }
    }
}

extern "C" void kernel_launch(void* const* d_in, const int* in_sizes, int n_in,
                              void* d_out, int out_size, void* d_ws, size_t ws_size,
                              hipStream_t stream) {
    const float* x      = (const float*)d_in[0];
    const int*   ei     = (const int*)  d_in[1];
    const float* ev     = (const float*)d_in[2];
    const float* pos    = (const float*)d_in[3];
    const float* qkv_w  = (const float*)d_in[4];
    const float* qkv_b  = (const float*)d_in[5];
    const float* proj_w = (const float*)d_in[6];
    const float* proj_b = (const float*)d_in[7];
    const float* gate_w = (const float*)d_in[8];
    const float* gate_b = (const float*)d_in[9];
    float* out = (float*)d_out;

    const int E  = in_sizes[2];
    const int N  = in_sizes[0] / CH;
    const int nb = N / BSZ;

    char* ws = (char*)d_ws;
    int*   win = (int*)ws;                                   // nb*4096 B
    float* pg  = (float*)(ws + (size_t)nb * 4096);           // 4*N*4 B
    size_t off = (size_t)nb * 4096 + (size_t)4 * N * 4;
    ushort_t* qkv_wf  = (ushort_t*)(ws + off); off += 48 * 8 * 64 * 8 * 2;
    ushort_t* proj_wf = (ushort_t*)(ws + off); off += 16 * 8 * 64 * 8 * 2;

    hipMemsetAsync(win, 0xFF, (size_t)nb * 4096, stream);    // win = -1
    edge_win_kernel<<<(E + 255) / 256, 256, 0, stream>>>(ei, E, nb, win);
    int prep_blocks = 96 + (4 * N + 255) / 256;
    prep_kernel<<<prep_blocks, 256, 0, stream>>>(qkv_w, proj_w, qkv_wf, proj_wf,
                                                 pos, gate_w, pg, N);
    fused_attn<<<nb / 2, 256, 0, stream>>>(x, qkv_wf, qkv_b, win, ev, pg,
                                           proj_wf, proj_b, gate_w, gate_b,
                                           out, N);
}

// Round 21
// 223.250 us; speedup vs baseline: 1.4083x; 1.4083x over previous
//
#include <hip/hip_runtime.h>
#include <math.h>

#define BSZ 32
#define CH  256

typedef short  bf16x8 __attribute__((ext_vector_type(8)));
typedef float  f32x4  __attribute__((ext_vector_type(4)));
typedef unsigned short ushort_t;
typedef unsigned int   uint_t;

#define MFMA(a, b, c) __builtin_amdgcn_mfma_f32_16x16x32_bf16((a), (b), (c), 0, 0, 0)

__device__ __forceinline__ ushort_t f2b(float f) {
    uint_t u = __builtin_bit_cast(uint_t, f);
    uint_t r = (u + 0x7FFFu + ((u >> 16) & 1u)) >> 16;   // RTNE
    return (ushort_t)r;
}
__device__ __forceinline__ float b2f(ushort_t u) {
    uint_t v = ((uint_t)u) << 16;
    return __builtin_bit_cast(float, v);
}
__device__ __forceinline__ uint_t pk2(float a, float b) {
    return (uint_t)f2b(a) | ((uint_t)f2b(b) << 16);
}

// ---------------- kernel 1: per-cell winning edge (last write wins) -------
__global__ void edge_win_kernel(const int* __restrict__ ei, int E, int nb,
                                int* __restrict__ win) {
    int e = blockIdx.x * blockDim.x + threadIdx.x;
    if (e >= E) return;
    int r = ei[e];
    int c = ei[E + e];
    int br = r >> 5, bc = c >> 5;
    if (br == bc && br < nb) {
        atomicMax(&win[br * (BSZ * BSZ) + (r & 31) * BSZ + (c & 31)], e);
    }
}

// ---------------- kernel 2: weights->frag layout + per-node gate proj -----
// blocks [0,96): wconv (qkv 48 tiles + proj 16 tiles, fragment layout)
// blocks [96,..): pg[h*N+n] = dot(pos[n], gate_w[h][0:3])
__global__ void prep_kernel(const float* __restrict__ qkv_w,
                            const float* __restrict__ proj_w,
                            ushort_t* __restrict__ qkv_wf,
                            ushort_t* __restrict__ proj_wf,
                            const float* __restrict__ pos,
                            const float* __restrict__ gate_w,
                            float* __restrict__ pg, int N) {
    int b = blockIdx.x;
    if (b < 96) {
        int i = b * 256 + threadIdx.x;   // (tile,ks,lane)
        int lane = i & 63, ks = (i >> 6) & 7, tile = i >> 9;
        int l15 = lane & 15, lg = lane >> 4;
        if (tile < 48) {
            const float* src = qkv_w + (size_t)(tile * 16 + l15) * 256 + ks * 32 + lg * 8;
            ushort_t* dst = qkv_wf + (size_t)i * 8;
            #pragma unroll
            for (int e = 0; e < 8; ++e) dst[e] = f2b(src[e]);
        }
        if (tile < 16) {
            const float* src = proj_w + (size_t)(tile * 16 + l15) * 256 + ks * 32 + lg * 8;
            ushort_t* dst = proj_wf + (size_t)i * 8;
            #pragma unroll
            for (int e = 0; e < 8; ++e) dst[e] = f2b(src[e]);
        }
    } else {
        int idx = (b - 96) * 256 + threadIdx.x;   // 0 .. 4N-1
        if (idx >= 4 * N) return;
        int h = idx / N;
        int n = idx - h * N;
        pg[(size_t)h * N + n] = pos[n * 3 + 0] * gate_w[h * 4 + 0]
                              + pos[n * 3 + 1] * gate_w[h * 4 + 1]
                              + pos[n * 3 + 2] * gate_w[h * 4 + 2];
    }
}

// ---------------- fused kernel: BM=64, wave = head, in-wave everything ----
// FINAL configuration (measured wall-best 223.5/223.6 us, absmax 0.00195).
// 256 threads (4 waves). Wave h computes q,k,v for ch [h*64,(h+1)*64) of
// BOTH leaves, converts D-frags via the wave-private scr repack, runs
// scores/softmax/PV in registers. ev gathers hoisted to resolve under the
// v-GEMM + B2. launch_bounds(256,2): the 124-VGPR working set needs the
// 2-waves/SIMD budget (4 waves/SIMD forces VGPR=64 -> scratch spills, R20).
// LDS: xb 32K (-> xo overlay post-B2) + scr 4x1216 = 37632 B.
#define LS_SCR 32768
#define LS_TOT 37632

__global__ __launch_bounds__(256, 2)
void fused_attn(const float* __restrict__ x,
                const ushort_t* __restrict__ qkv_wf,
                const float* __restrict__ qkv_b,
                const int* __restrict__ win,
                const float* __restrict__ ev,
                const float* __restrict__ pg,
                const ushort_t* __restrict__ proj_wf,
                const float* __restrict__ proj_b,
                const float* __restrict__ gate_w,
                const float* __restrict__ gate_b,
                float* __restrict__ out, int N)
{
    __shared__ __align__(16) char smem[LS_TOT];
    ushort_t* xb = (ushort_t*)(smem);
    ushort_t* xo = (ushort_t*)(smem);      // overlay: xb dead post-B2

    const int t = threadIdx.x;
    const int h = t >> 6, lane = t & 63, l15 = lane & 15, lg = lane >> 4;
    const int bi = blockIdx.x, mbase = bi * 64;
    ushort_t* scr = (ushort_t*)(smem + LS_SCR + h * 1216);

    // ---- P1: stage x -> bf16 LDS (swz8) ---------------------------------
    #pragma unroll
    for (int i = 0; i < 16; ++i) {
        int flat = i * 1024 + t * 4;
        int r = flat >> 8, c = flat & 255;
        float4 xv = *(const float4*)&x[(size_t)(mbase + r) * CH + c];
        uint2 wv; wv.x = pk2(xv.x, xv.y); wv.y = pk2(xv.z, xv.w);
        *(uint2*)&xb[r * 256 + (c ^ ((r & 7) << 3))] = wv;
    }
    __syncthreads();   // B1

    const int slB = (l15 & 7) << 3;
    const f32x4 zf = {0.f, 0.f, 0.f, 0.f};

    // wave-private 16x32 repack (R10-proven): D-frag pair -> A/B-frag.
    auto repack16 = [&](f32x4 a0, f32x4 a1) -> bf16x8 {
        uint2 w0, w1;
        w0.x = pk2(a0[0], a0[1]); w0.y = pk2(a0[2], a0[3]);
        w1.x = pk2(a1[0], a1[1]); w1.y = pk2(a1[2], a1[3]);
        *(uint2*)&scr[l15 * 38 + lg * 4]      = w0;
        *(uint2*)&scr[l15 * 38 + 16 + lg * 4] = w1;
        return *(const bf16x8*)&scr[l15 * 38 + lg * 8];
    };

    bf16x8 qld[2][2][2], kld[2][2][2], vf[2][4];

#define QK_SECTION(TB, DST)                                                   \
    _Pragma("unroll")                                                         \
    for (int p = 0; p < 2; ++p) {                                             \
        const int T0 = (TB) + p * 2, T1 = T0 + 1;                             \
        bf16x8 W0[8], W1[8];                                                  \
        _Pragma("unroll")                                                     \
        for (int ks = 0; ks < 8; ++ks) {                                      \
            W0[ks] = *(const bf16x8*)(qkv_wf                                  \
                        + ((size_t)(T0 * 8 + ks)) * 512 + lane * 8);          \
            W1[ks] = *(const bf16x8*)(qkv_wf                                  \
                        + ((size_t)(T1 * 8 + ks)) * 512 + lane * 8);          \
        }                                                                     \
        f32x4 a0[4], a1[4];                                                   \
        _Pragma("unroll")                                                     \
        for (int m = 0; m < 4; ++m) { a0[m] = zf; a1[m] = zf; }               \
        __builtin_amdgcn_s_setprio(1);                                        \
        _Pragma("unroll")                                                     \
        for (int ks = 0; ks < 8; ++ks) {                                      \
            int k0 = (ks * 32 + lg * 8) ^ slB;                                \
            _Pragma("unroll")                                                 \
            for (int m = 0; m < 4; ++m) {                                     \
                bf16x8 xf = *(const bf16x8*)&xb[(m * 16 + l15) * 256 + k0];   \
                a0[m] = MFMA(W0[ks], xf, a0[m]);                              \
                a1[m] = MFMA(W1[ks], xf, a1[m]);                              \
            }                                                                 \
        }                                                                     \
        __builtin_amdgcn_s_setprio(0);                                        \
        f32x4 b0v = *(const f32x4*)&qkv_b[T0 * 16 + lg * 4];                  \
        f32x4 b1v = *(const f32x4*)&qkv_b[T1 * 16 + lg * 4];                  \
        _Pragma("unroll")                                                     \
        for (int m = 0; m < 4; ++m) { a0[m] += b0v; a1[m] += b1v; }           \
        _Pragma("unroll")                                                     \
        for (int gl = 0; gl < 2; ++gl)                                        \
            _Pragma("unroll")                                                 \
            for (int rt = 0; rt < 2; ++rt)                                    \
                DST[gl][rt][p] = repack16(a0[gl * 2 + rt], a1[gl * 2 + rt]);  \
    }

    // ---- P2: q section (swapped: D[ch][row]) -> qld B-frags -------------
    QK_SECTION(h * 4, qld)
    // ---- P3: k section -> kld A-frags -----------------------------------
    QK_SECTION(16 + h * 4, kld)

    // ---- preload win / pgate, then HOISTED ev gathers -------------------
    uint4  wv4[2][2][2];
    float4 pgc[2][2];
    float  pgr[2][2];
    #pragma unroll
    for (int gl = 0; gl < 2; ++gl) {
        int cb = mbase + gl * 32;
        #pragma unroll
        for (int qt = 0; qt < 2; ++qt) {
            int qi = qt * 16 + l15;
            wv4[gl][qt][0] = *(const uint4*)&win[(size_t)(bi * 2 + gl) * 1024
                                                + qi * 32 + lg * 4];
            wv4[gl][qt][1] = *(const uint4*)&win[(size_t)(bi * 2 + gl) * 1024
                                                + qi * 32 + 16 + lg * 4];
            pgr[gl][qt] = pg[(size_t)h * N + cb + qi];
        }
        pgc[gl][0] = *(const float4*)&pg[(size_t)h * N + cb + lg * 4];
        pgc[gl][1] = *(const float4*)&pg[(size_t)h * N + cb + 16 + lg * 4];
    }
    // ev gathers issued HERE: resolve under the v-GEMM + B2 (off the
    // post-B2 softmax critical chain).
    float evv[2][2][8];
    #pragma unroll
    for (int gl = 0; gl < 2; ++gl)
        #pragma unroll
        for (int qt = 0; qt < 2; ++qt)
            #pragma unroll
            for (int kt = 0; kt < 2; ++kt) {
                const int* wp = (const int*)&wv4[gl][qt][kt];
                #pragma unroll
                for (int j = 0; j < 4; ++j) {
                    int e = wp[j];
                    evv[gl][qt][kt * 4 + j] = ev[e < 0 ? 0 : e];
                }
            }

    // ---- P4: v section (non-swapped: D[row][ch]) -> vf A-frags ----------
    #pragma unroll
    for (int ct = 0; ct < 4; ++ct) {
        int T = 32 + h * 4 + ct;
        bf16x8 W[8];
        #pragma unroll
        for (int ks = 0; ks < 8; ++ks)
            W[ks] = *(const bf16x8*)(qkv_wf + ((size_t)(T * 8 + ks)) * 512 + lane * 8);
        f32x4 a[4];
        #pragma unroll
        for (int m = 0; m < 4; ++m) a[m] = zf;
        __builtin_amdgcn_s_setprio(1);
        #pragma unroll
        for (int ks = 0; ks < 8; ++ks) {
            int k0 = (ks * 32 + lg * 8) ^ slB;
            #pragma unroll
            for (int m = 0; m < 4; ++m) {
                bf16x8 xf = *(const bf16x8*)&xb[(m * 16 + l15) * 256 + k0];
                a[m] = MFMA(xf, W[ks], a[m]);
            }
        }
        __builtin_amdgcn_s_setprio(0);
        float bvs = qkv_b[T * 16 + l15];
        f32x4 bb = {bvs, bvs, bvs, bvs};
        #pragma unroll
        for (int m = 0; m < 4; ++m) a[m] += bb;
        vf[0][ct] = repack16(a[0], a[1]);
        vf[1][ct] = repack16(a[2], a[3]);
    }
    __syncthreads();   // B2: all waves' xb reads done -> xo overlay safe

    const float gw3v = gate_w[h * 4 + 3];
    const float gbv  = gate_b[h];
    const float g3b  = gw3v + gbv;

    // ---- P5: per-leaf attention (all in-wave) ---------------------------
    #pragma unroll
    for (int gl = 0; gl < 2; ++gl) {
        // scores MFMA (A=k M=kj, B=q N=qi)
        f32x4 s[2][2];
        #pragma unroll
        for (int qt = 0; qt < 2; ++qt) { s[qt][0] = zf; s[qt][1] = zf; }
        __builtin_amdgcn_s_setprio(1);
        #pragma unroll
        for (int qt = 0; qt < 2; ++qt)
            #pragma unroll
            for (int p = 0; p < 2; ++p)
                #pragma unroll
                for (int kt = 0; kt < 2; ++kt)
                    s[qt][kt] = MFMA(kld[gl][kt][p], qld[gl][qt][p], s[qt][kt]);
        __builtin_amdgcn_s_setprio(0);

        // softmax + gate; kj=32 via mean of raw scores (linearity)
        bf16x8 cfr[2];
        #pragma unroll
        for (int qt = 0; qt < 2; ++qt) {
            int qi = qt * 16 + l15;
            float r[8], gt[8];
            float rawsum = 0.f;
            #pragma unroll
            for (int kt = 0; kt < 2; ++kt) {
                const int* wp = (const int*)&wv4[gl][qt][kt];
                #pragma unroll
                for (int j = 0; j < 4; ++j) {
                    int kj = kt * 16 + lg * 4 + j;
                    bool fixed = (kj == qi);
                    bool valid = wp[j] >= 0;
                    float e3 = evv[gl][qt][kt * 4 + j];
                    float sb = fixed ? 1.0f : (valid ? e3 : -INFINITY);
                    float pgcv = ((const float*)&pgc[gl][kt])[j];
                    float g = fixed ? g3b
                            : (valid ? (pgcv - pgr[gl][qt] + e3 * gw3v + gbv) : 0.0f);
                    float sraw = s[qt][kt][j];
                    rawsum += sraw;
                    r[kt * 4 + j]  = sraw * 0.125f + sb;
                    gt[kt * 4 + j] = g;
                }
            }
            rawsum += __shfl_xor(rawsum, 16);
            rawsum += __shfl_xor(rawsum, 32);
            float r2 = rawsum * (0.125f / 32.0f) + 1.0f;

            float m = fmaxf(fmaxf(fmaxf(r[0], r[1]), fmaxf(r[2], r[3])),
                            fmaxf(fmaxf(r[4], r[5]), fmaxf(r[6], r[7])));
            m = fmaxf(m, r2);
            m = fmaxf(m, __shfl_xor(m, 16));
            m = fmaxf(m, __shfl_xor(m, 32));
            float sum = 0.f;
            #pragma unroll
            for (int i = 0; i < 8; ++i) { r[i] = __expf(r[i] - m); sum += r[i]; }
            sum += __shfl_xor(sum, 16);
            sum += __shfl_xor(sum, 32);
            float e2 = __expf(r2 - m);
            float inv = 1.0f / (sum + e2);
            float comb32 = e2 * inv + g3b;
            float cadd = comb32 * 0.03125f;   // fold kj=32 PV into every entry
            f32x4 ra = {r[0] * inv + gt[0] + cadd, r[1] * inv + gt[1] + cadd,
                        r[2] * inv + gt[2] + cadd, r[3] * inv + gt[3] + cadd};
            f32x4 rb = {r[4] * inv + gt[4] + cadd, r[5] * inv + gt[5] + cadd,
                        r[6] * inv + gt[6] + cadd, r[7] * inv + gt[7] + cadd};
            cfr[qt] = repack16(ra, rb);       // B-frag: l15=qi, lg*8+e=kj
        }

        // PV MFMA (A=v M=ch, B=comb N=qi) -> xo (xb overlay)
        __builtin_amdgcn_s_setprio(1);
        #pragma unroll
        for (int ct = 0; ct < 4; ++ct) {
            #pragma unroll
            for (int qt = 0; qt < 2; ++qt) {
                f32x4 a2 = zf;
                a2 = MFMA(vf[gl][ct], cfr[qt], a2);
                int qi = qt * 16 + l15;
                uint2 wv;
                wv.x = pk2(a2[0], a2[1]);
                wv.y = pk2(a2[2], a2[3]);
                int c0 = h * 64 + ct * 16 + lg * 4;
                *(uint2*)&xo[gl * 8192 + qi * 256 + (c0 ^ ((l15 & 7) << 3))] = wv;
            }
        }
        __builtin_amdgcn_s_setprio(0);
    }
    __syncthreads();   // B3: xo read cross-wave by proj

    // ---- P6: proj (wave h: tiles h*4+i), 2-deep weight pipeline ---------
    {
        const int slR = (l15 & 7) << 3;
        bf16x8 pwA[4], pwB[4];
        f32x4 pacc[4][4];
        #pragma unroll
        for (int i = 0; i < 4; ++i)
            #pragma unroll
            for (int rt = 0; rt < 4; ++rt) pacc[i][rt] = zf;

#define LOADPW(dst, kss) { _Pragma("unroll")                                  \
        for (int i_ = 0; i_ < 4; ++i_)                                        \
            dst[i_] = *(const bf16x8*)(proj_wf                                \
                + ((size_t)((h * 4 + i_) * 8 + (kss))) * 512 + lane * 8); }

#define PCOMP(pw, kss) { int k0_ = (kss) * 32 + lg * 8;                       \
        _Pragma("unroll")                                                     \
        for (int rt_ = 0; rt_ < 4; ++rt_) {                                   \
            bf16x8 b_ = *(const bf16x8*)&xo[(rt_ >> 1) * 8192                 \
                         + ((rt_ & 1) * 16 + l15) * 256 + (k0_ ^ slR)];       \
            _Pragma("unroll")                                                 \
            for (int i_ = 0; i_ < 4; ++i_)                                    \
                pacc[i_][rt_] = MFMA(pw[i_], b_, pacc[i_][rt_]);              \
        } }

        LOADPW(pwA, 0); LOADPW(pwB, 1);
        __builtin_amdgcn_s_setprio(1);
        PCOMP(pwA, 0);  LOADPW(pwA, 2);
        PCOMP(pwB, 1);  LOADPW(pwB, 3);
        PCOMP(pwA, 2);  LOADPW(pwA, 4);
        PCOMP(pwB, 3);  LOADPW(pwB, 5);
        PCOMP(pwA, 4);  LOADPW(pwA, 6);
        PCOMP(pwB, 5);  LOADPW(pwB, 7);
        PCOMP(pwA, 6);
        PCOMP(pwB, 7);
        __builtin_amdgcn_s_setprio(0);

        #pragma unroll
        for (int i = 0; i < 4; ++i) {
            int n0 = (h * 4 + i) * 16;
            f32x4 bv = *(const f32x4*)&proj_b[n0 + lg * 4];
            #pragma unroll
            for (int rt = 0; rt < 4; ++rt) {
                f32x4 o = pacc[i][rt] + bv;
                int row = mbase + (rt >> 1) * 32 + (rt & 1) * 16 + l15;
                *(f32x4*)&out[(size_t)row * 256 + n0 + lg * 4] = o;
            }
        }
    }
}

extern "C" void kernel_launch(void* const* d_in, const int* in_sizes, int n_in,
                              void* d_out, int out_size, void* d_ws, size_t ws_size,
                              hipStream_t stream) {
    const float* x      = (const float*)d_in[0];
    const int*   ei     = (const int*)  d_in[1];
    const float* ev     = (const float*)d_in[2];
    const float* pos    = (const float*)d_in[3];
    const float* qkv_w  = (const float*)d_in[4];
    const float* qkv_b  = (const float*)d_in[5];
    const float* proj_w = (const float*)d_in[6];
    const float* proj_b = (const float*)d_in[7];
    const float* gate_w = (const float*)d_in[8];
    const float* gate_b = (const float*)d_in[9];
    float* out = (float*)d_out;

    const int E  = in_sizes[2];
    const int N  = in_sizes[0] / CH;
    const int nb = N / BSZ;

    char* ws = (char*)d_ws;
    int*   win = (int*)ws;                                   // nb*4096 B
    float* pg  = (float*)(ws + (size_t)nb * 4096);           // 4*N*4 B
    size_t off = (size_t)nb * 4096 + (size_t)4 * N * 4;
    ushort_t* qkv_wf  = (ushort_t*)(ws + off); off += 48 * 8 * 64 * 8 * 2;
    ushort_t* proj_wf = (ushort_t*)(ws + off); off += 16 * 8 * 64 * 8 * 2;

    hipMemsetAsync(win, 0xFF, (size_t)nb * 4096, stream);    // win = -1
    edge_win_kernel<<<(E + 255) / 256, 256, 0, stream>>>(ei, E, nb, win);
    int prep_blocks = 96 + (4 * N + 255) / 256;
    prep_kernel<<<prep_blocks, 256, 0, stream>>>(qkv_w, proj_w, qkv_wf, proj_wf,
                                                 pos, gate_w, pg, N);
    fused_attn<<<nb / 2, 256, 0, stream>>>(x, qkv_wf, qkv_b, win, ev, pg,
                                           proj_wf, proj_b, gate_w, gate_b,
                                           out, N);
}